// Round 13
// baseline (90.684 us; speedup 1.0000x reference)
//
#include <hip/hip_runtime.h>
#include <math.h>

#define L_ 4096
#define NROW 8192   // B*L
#define LP 4144     // L + 48 (24 pad each side)

typedef __attribute__((ext_vector_type(8))) short bf16x8;
typedef __attribute__((ext_vector_type(4))) float f32x4;

__device__ __forceinline__ float sigmoidf_(float x) { return 1.f / (1.f + __expf(-x)); }
__device__ __forceinline__ float siluf_(float x) { return x * sigmoidf_(x); }

__device__ __forceinline__ unsigned short f2bf(float x) {
    union { float f; unsigned int u; } v; v.f = x;
    unsigned int r = v.u + 0x7fff + ((v.u >> 16) & 1);   // RNE
    return (unsigned short)(r >> 16);
}
__device__ __forceinline__ float bf2f(unsigned short u) {
    union { unsigned int u; float f; } v; v.u = ((unsigned int)u) << 16;
    return v.f;
}

__device__ __forceinline__ void gll16(const void* g, void* l) {
    auto gp = reinterpret_cast<const __attribute__((address_space(1))) unsigned int*>(
        reinterpret_cast<uintptr_t>(g));
    auto lp = reinterpret_cast<__attribute__((address_space(3))) unsigned int*>(
        reinterpret_cast<uintptr_t>(l));
    __builtin_amdgcn_global_load_lds(gp, lp, 16, 0, 0);
}

// ---------------------------------------------------------------------------
// bf16 MFMA GEMM (NT), K=512, BN=64, BK=64 (128B rows), BM=64, 4 waves.
// TRIPLE-buffered counted-vmcnt loop (1 raw barrier/iter; loads span 2 iters,
// vmcnt never drained to 0 mid-loop). In-row XOR swizzle (r10-verified:
// SQ_LDS_BANK_CONFLICT = 0, staging 128B segments coalesced).
// Per iter: STAGE(s+2) -> COMPUTE(s) -> s_waitcnt lgkmcnt(0) vmcnt(L) ->
// s_barrier.  lgkmcnt(0) closes the ds_read-straggler race (buf s%3 is
// overwritten at iter s+1); vmcnt(L) waits only the OLDER stage (t_{s+1}),
// keeping t_{s+2}'s L loads in flight across the barrier.
// EPI 0:  silu -> outF f32 [row*512+col]                    (out-proj)
// EPI 3:  gate: g=sigmoid(silu(acc+bias[col])); vv=bf2f(A_pad[row,col]);
//         oo=extraF0[row*512+col]*extraF1[row]*extraF2[col];
//         outB0 = bf16(g*vv + (1-g)*oo)                     (A = vpad, APAD)
// EPI 10: fused qkv+wp. bn/512 = kind: 0 q (rms+rope->outB0),
//         1 k (rms+rope->kpad outB1), 2 v (silu->vpad outB2),
//         3 wp (silu(acc+bias)->outF[row*16+fr]).
// ---------------------------------------------------------------------------
template<int EPI, int BM, bool APAD>
__global__ __launch_bounds__(256) void mfma_gemm(
    const unsigned short* __restrict__ A,
    const unsigned short* __restrict__ W0,
    const unsigned short* __restrict__ W1,
    const unsigned short* __restrict__ W2,
    float* __restrict__ outF,
    unsigned short* __restrict__ outB0,
    unsigned short* __restrict__ outB1,
    unsigned short* __restrict__ outB2,
    const float* __restrict__ bias,
    const float* __restrict__ extraF0,
    const float* __restrict__ extraF1,
    const float* __restrict__ extraF2)
{
    constexpr int MF = BM / 64;          // m-frags per wave
    constexpr int WR = BM / 4;           // rows per wave
    constexpr int BUFSZ = BM * 128 + 8192;
    __shared__ __align__(128) unsigned char lds[3][BUFSZ];

    const int tid = threadIdx.x;
    const int wid = tid >> 6, lane = tid & 63;
    const int fr = lane & 15, fq = lane >> 4;

    // XCD-aware bijective swizzle (nwg % 8 == 0)
    const int nwg = gridDim.x * gridDim.y;
    const int lin = blockIdx.y * gridDim.x + blockIdx.x;
    const int mapped = (lin & 7) * (nwg >> 3) + (lin >> 3);
    const int bx = mapped % gridDim.x, by = mapped / gridDim.x;
    const int bm = by * BM, bn = bx * 64;

    const unsigned short* Wsel = W0;
    int bnl = bn;
    if (EPI == 10) {
        int kind = bn >> 9;
        if (kind == 0)      { Wsel = W0; bnl = bn; }
        else if (kind <= 2) { Wsel = W1; bnl = bn - 512; }
        else                { Wsel = W2; bnl = bn - 1536; }
    }

    const int apadoff = APAD ? (24 + (bm >> 12) * 48) : 0;
    // staging: lane -> (row = lane>>3, slot = (lane&7)^(row&7)); 128B segments
    const int srow = lane >> 3;
    const int sslot = (lane & 7) ^ srow;
    const unsigned char* gA = (const unsigned char*)A +
        (size_t)(bm + apadoff + wid * WR + srow) * 1024 + sslot * 16;
    const unsigned char* gB = (const unsigned char*)Wsel +
        (size_t)(bnl + wid * 16 + srow) * 1024 + sslot * 16;

    f32x4 acc[MF][4];
    #pragma unroll
    for (int m = 0; m < MF; ++m)
        #pragma unroll
        for (int n = 0; n < 4; ++n)
            acc[m][n] = (f32x4){0.f, 0.f, 0.f, 0.f};

    auto STAGE = [&](int bsel, int k0) {
        unsigned char* lA = lds[bsel] + wid * (WR * 128);
        unsigned char* lB = lds[bsel] + BM * 128 + wid * 2048;
        #pragma unroll
        for (int it = 0; it < WR / 8; ++it)
            gll16(gA + (size_t)it * 8 * 1024 + k0 * 2, lA + it * 1024);
        #pragma unroll
        for (int it = 0; it < 2; ++it)
            gll16(gB + (size_t)it * 8 * 1024 + k0 * 2, lB + it * 1024);
    };
    auto COMPUTE = [&](int bsel) {
        const unsigned char* As = lds[bsel];
        const unsigned char* Bs = lds[bsel] + BM * 128;
        bf16x8 af[MF][2], bfv[4][2];
        #pragma unroll
        for (int m = 0; m < MF; ++m) {
            int ra = wid * WR + m * 16 + fr;
            #pragma unroll
            for (int ks = 0; ks < 2; ++ks)
                af[m][ks] = *(const bf16x8*)(As + ra * 128 + (((ks * 4 + fq) ^ (fr & 7)) << 4));
        }
        #pragma unroll
        for (int n = 0; n < 4; ++n) {
            int rbr = n * 16 + fr;
            #pragma unroll
            for (int ks = 0; ks < 2; ++ks)
                bfv[n][ks] = *(const bf16x8*)(Bs + rbr * 128 + (((ks * 4 + fq) ^ (fr & 7)) << 4));
        }
        #pragma unroll
        for (int ks = 0; ks < 2; ++ks)
            #pragma unroll
            for (int m = 0; m < MF; ++m)
                #pragma unroll
                for (int n = 0; n < 4; ++n)
                    acc[m][n] = __builtin_amdgcn_mfma_f32_16x16x32_bf16(
                        af[m][ks], bfv[n][ks], acc[m][n], 0, 0, 0);
    };

    // loads per STAGE (all counted: only gll16 ops touch vmcnt in the loop)
    constexpr int LDS_LOADS = WR / 8 + 2;   // BM=64 -> 4, BM=128 -> 6

    // prologue: tiles 0,1 in flight; wait tile 0 (tile 1's loads remain)
    STAGE(0, 0);
    STAGE(1, 64);
    if constexpr (LDS_LOADS == 4) asm volatile("s_waitcnt vmcnt(4)" ::: "memory");
    else                          asm volatile("s_waitcnt vmcnt(6)" ::: "memory");
    __builtin_amdgcn_s_barrier();

    #pragma unroll
    for (int s = 0; s < 8; ++s) {
        if (s + 2 < 8) STAGE((s + 2) % 3, (s + 2) * 64);
        COMPUTE(s % 3);
        if (s < 6) {
            // drain own ds_reads (buf s%3 overwritten next iter) + wait the
            // older stage's loads; newest stage's L loads stay in flight
            if constexpr (LDS_LOADS == 4)
                asm volatile("s_waitcnt lgkmcnt(0) vmcnt(4)" ::: "memory");
            else
                asm volatile("s_waitcnt lgkmcnt(0) vmcnt(6)" ::: "memory");
            __builtin_amdgcn_s_barrier();
        } else if (s == 6) {
            asm volatile("s_waitcnt lgkmcnt(0) vmcnt(0)" ::: "memory");
            __builtin_amdgcn_s_barrier();
        }
    }

    const int rb = bm + wid * WR + fq * 4;

    if (EPI == 10) {
        const int kind = bn >> 9;
        if (kind <= 1) {
            // rms + rope fused epilogue (wave column strip == one head)
            const float* nw = (kind == 0) ? extraF1 : extraF2;
            const float nw0 = nw[fr], nw1 = nw[16 + fr], nw2 = nw[32 + fr], nw3 = nw[48 + fr];
            const int hh = (bn & 511) >> 6;
            const float lg = -0.41524101186092029f;   // -log2(10000)/32
            float f0 = exp2f(lg * (float)fr);
            float f1 = exp2f(lg * (float)(16 + fr));
            float s0, c0, s1, c1;
            sincosf((float)hh * f0, &s0, &c0);
            sincosf((float)hh * f1, &s1, &c1);
            unsigned short* dstb = (kind == 0) ? outB0 : outB1;
            #pragma unroll
            for (int m = 0; m < MF; ++m) {
                #pragma unroll
                for (int j = 0; j < 4; ++j) {
                    int row = rb + m * 16 + j;
                    float v0 = siluf_(acc[m][0][j]);
                    float v1 = siluf_(acc[m][1][j]);
                    float v2 = siluf_(acc[m][2][j]);
                    float v3 = siluf_(acc[m][3][j]);
                    float ss = v0 * v0 + v1 * v1 + v2 * v2 + v3 * v3;
                    ss += __shfl_xor(ss, 1, 64);
                    ss += __shfl_xor(ss, 2, 64);
                    ss += __shfl_xor(ss, 4, 64);
                    ss += __shfl_xor(ss, 8, 64);
                    float inv = rsqrtf(ss * (1.f / 64.f) + 1e-6f);
                    float y0 = v0 * inv * nw0, y1 = v1 * inv * nw1;
                    float y2 = v2 * inv * nw2, y3 = v3 * inv * nw3;
                    float o0 = y0 * c0 - y2 * s0;
                    float o1 = y1 * c1 - y3 * s1;
                    float o2 = y0 * s0 + y2 * c0;
                    float o3 = y1 * s1 + y3 * c1;
                    size_t rr = (kind == 0) ? (size_t)row
                                            : (size_t)(row + 24 + (row >> 12) * 48);
                    unsigned short* dp = dstb + rr * 512 + hh * 64 + fr;
                    dp[0]  = f2bf(o0);
                    dp[16] = f2bf(o1);
                    dp[32] = f2bf(o2);
                    dp[48] = f2bf(o3);
                }
            }
        } else if (kind == 2) {
            #pragma unroll
            for (int m = 0; m < MF; ++m)
                #pragma unroll
                for (int j = 0; j < 4; ++j) {
                    int row = rb + m * 16 + j;
                    size_t rr = (size_t)(row + 24 + (row >> 12) * 48);
                    #pragma unroll
                    for (int n = 0; n < 4; ++n) {
                        int lc = (bn - 1024) + n * 16 + fr;
                        outB2[rr * 512 + lc] = f2bf(siluf_(acc[m][n][j]));
                    }
                }
        } else {
            // wp: only cols 1536..1551 (n==0, fr 0..15)
            #pragma unroll
            for (int m = 0; m < MF; ++m)
                #pragma unroll
                for (int j = 0; j < 4; ++j) {
                    int row = rb + m * 16 + j;
                    outF[(size_t)row * 16 + fr] = siluf_(acc[m][0][j] + bias[fr]);
                }
        }
    } else {
        #pragma unroll
        for (int m = 0; m < MF; ++m) {
            #pragma unroll
            for (int j = 0; j < 4; ++j) {
                int row = rb + m * 16 + j;
                #pragma unroll
                for (int n = 0; n < 4; ++n) {
                    int col = bn + n * 16 + fr;
                    float t = acc[m][n][j];
                    if (EPI == 0) {
                        outF[(size_t)row * 512 + col] = siluf_(t);
                    } else {  // EPI 3
                        float g = sigmoidf_(siluf_(t + bias[col]));
                        size_t rr = (size_t)(row + 24 + (row >> 12) * 48);
                        float vv = bf2f(A[rr * 512 + col]);
                        float oo = extraF0[(size_t)row * 512 + col] * extraF1[row] * extraF2[col];
                        outB0[(size_t)row * 512 + col] = f2bf(g * vv + (1.f - g) * oo);
                    }
                }
            }
        }
    }
}

// ---------------------------------------------------------------------------
__global__ __launch_bounds__(256) void conv_bf16(
    const float* __restrict__ in, unsigned short* __restrict__ out, int n4)
{
    int i = blockIdx.x * 256 + threadIdx.x;
    if (i < n4) {
        float4 v = ((const float4*)in)[i];
        ushort4 o;
        o.x = f2bf(v.x); o.y = f2bf(v.y); o.z = f2bf(v.z); o.w = f2bf(v.w);
        ((ushort4*)out)[i] = o;
    }
}

__global__ __launch_bounds__(256) void conv_w5(
    const float* __restrict__ Wq, const float* __restrict__ Wkv,
    const float* __restrict__ Wg, const float* __restrict__ Wout,
    unsigned short* __restrict__ wqb, unsigned short* __restrict__ wkvb,
    unsigned short* __restrict__ wgb, unsigned short* __restrict__ woutb)
{
    int y = blockIdx.y;
    int i = blockIdx.x * 256 + threadIdx.x;
    const float* src;
    unsigned short* dst;
    if (y == 0)      { src = Wq;            dst = wqb; }
    else if (y == 1) { src = Wkv;           dst = wkvb; }
    else if (y == 2) { src = Wkv + 262144;  dst = wkvb + 262144; }
    else if (y == 3) { src = Wg;            dst = wgb; }
    else             { src = Wout;          dst = woutb; }
    float4 v = ((const float4*)src)[i];
    ushort4 o;
    o.x = f2bf(v.x); o.y = f2bf(v.y); o.z = f2bf(v.z); o.w = f2bf(v.w);
    ((ushort4*)dst)[i] = o;
}

// Wwin [16,512] -> padded [64,512] bf16
__global__ __launch_bounds__(256) void conv_wwin(
    const float* __restrict__ in, unsigned short* __restrict__ out)
{
    int idx = blockIdx.x * 256 + threadIdx.x;   // 32768
    out[idx] = (idx < 8192) ? f2bf(in[idx]) : (unsigned short)0;
}

// zero the 24-row pads of kpad/vpad (every launch; deterministic)
__global__ __launch_bounds__(256) void zero_pads(
    unsigned short* __restrict__ kpad, unsigned short* __restrict__ vpad)
{
    int gid = blockIdx.x * 256 + threadIdx.x;   // 12288 threads
    int e = gid * 8;
    int c = e & 511;
    int t = e >> 9;            // 0..191
    int r48 = t % 48;
    int b = (t / 48) & 1;
    int buf = t / 96;
    int row = b * LP + (r48 < 24 ? r48 : 4096 + r48);
    unsigned short* dst = (buf ? vpad : kpad) + (size_t)row * 512 + c;
    *(uint4*)dst = make_uint4(0u, 0u, 0u, 0u);
}

// ---------------------------------------------------------------------------
// Light fused attention. One block per (b, h, 64-row l-tile), 4 waves.
// ---------------------------------------------------------------------------
__global__ __launch_bounds__(256) void attn_fused(
    const unsigned short* __restrict__ qb,
    const unsigned short* __restrict__ kpad,
    const unsigned short* __restrict__ vpad,
    const float* __restrict__ wpb,
    float* __restrict__ att)
{
    __shared__ __align__(16) unsigned char smem[35328];
    unsigned short* Kl = (unsigned short*)smem;                 // 112x64, swizzled
    auto P_A = (unsigned short(*)[136])smem;                    // overlays K after QK^T
    auto Vt  = (unsigned short(*)[136])(smem + 17408);          // [64][136]
    float* widths = (float*)(smem + 34816);
    float* sharps = (float*)(smem + 35072);

    const int tid = threadIdx.x, wid = tid >> 6, lane = tid & 63;
    const int fr = lane & 15, fq = lane >> 4;
    const int bid = blockIdx.x;
    const int tile = bid & 63, h = (bid >> 6) & 7, b = bid >> 9;
    const int l0 = tile * 64;
    const int n0 = b * L_ + l0;
    const size_t win0 = ((size_t)(b * LP + l0)) * 512;

    // ---- K staging: 896 16B-slots, linear LDS dest, pre-swizzled source
    #pragma unroll
    for (int r = 0; r < 4; ++r) {
        if (r < 3 || wid < 2) {
            int sbase = r * 256 + wid * 64;
            int s = sbase + lane;
            int row = s >> 3;
            int sl = (lane & 7) ^ (row & 7);
            gll16((const unsigned char*)(kpad + win0 + (size_t)row * 512 + h * 64) + sl * 16,
                  smem + sbase * 16);
        }
    }

    // ---- Q frags direct from global
    const unsigned short* qrow = qb + (size_t)(n0 + wid * 16 + fr) * 512 + h * 64 + fq * 8;
    bf16x8 bq0 = *(const bf16x8*)qrow;
    bf16x8 bq1 = *(const bf16x8*)(qrow + 32);

    if (tid < 64) {
        float w_ = wpb[(size_t)(n0 + tid) * 16 + h];
        float s_ = wpb[(size_t)(n0 + tid) * 16 + 8 + h];
        widths[tid] = 24.f * sigmoidf_(w_) + 0.5f;
        sharps[tid] = 9.5f * sigmoidf_(s_) + 0.5f;
    }

    // ---- V transpose staging (quad groups)
    {
        int g = tid & 3, rr = tid >> 2;
        #pragma unroll
        for (int it = 0; it < 2; ++it) {
            int w_ = rr + it * 64;
            if (w_ < 112) {
                const unsigned short* src = vpad + win0 + (size_t)w_ * 512 + h * 64 + g * 16;
                uint4 a = *(const uint4*)src;
                uint4 c = *(const uint4*)(src + 8);
                #pragma unroll
                for (int jj = 0; jj < 4; ++jj) {
                    unsigned int u = ((unsigned int*)&a)[jj];
                    Vt[g * 16 + jj * 2    ][w_] = (unsigned short)(u & 0xffff);
                    Vt[g * 16 + jj * 2 + 1][w_] = (unsigned short)(u >> 16);
                }
                #pragma unroll
                for (int jj = 0; jj < 4; ++jj) {
                    unsigned int u = ((unsigned int*)&c)[jj];
                    Vt[g * 16 + 8 + jj * 2    ][w_] = (unsigned short)(u & 0xffff);
                    Vt[g * 16 + 8 + jj * 2 + 1][w_] = (unsigned short)(u >> 16);
                }
            }
        }
        *(uint2*)&Vt[rr][112 + g * 4] = make_uint2(0u, 0u);
    }

    __syncthreads();

    // ---- QK^T: S^T[w][l], swizzled K reads
    f32x4 sacc[7];
    #pragma unroll
    for (int mf = 0; mf < 7; ++mf) sacc[mf] = (f32x4){0.f, 0.f, 0.f, 0.f};
    #pragma unroll
    for (int mf = 0; mf < 7; ++mf) {
        int row = mf * 16 + fr;
        #pragma unroll
        for (int ks = 0; ks < 2; ++ks) {
            const unsigned short* kp = Kl + (size_t)row * 64 + ((((ks << 2) + fq) ^ (row & 7)) << 3);
            bf16x8 ak = *(const bf16x8*)kp;
            sacc[mf] = (ks == 0)
                ? __builtin_amdgcn_mfma_f32_16x16x32_bf16(ak, bq0, sacc[mf], 0, 0, 0)
                : __builtin_amdgcn_mfma_f32_16x16x32_bf16(ak, bq1, sacc[mf], 0, 0, 0);
        }
    }

    __syncthreads();   // K dead in ALL waves -> P may overlay

    {
        int rr = tid >> 2, g = tid & 3;
        *(uint2*)&P_A[rr][112 + g * 4] = make_uint2(0u, 0u);
    }

    // ---- softmax
    const int rl = wid * 16 + fr;
    const float wd = widths[rl], sh = sharps[rl];
    float vals[28];
    float mx = -1e30f;
    #pragma unroll
    for (int mf = 0; mf < 7; ++mf) {
        #pragma unroll
        for (int jj = 0; jj < 4; ++jj) {
            int wv = mf * 16 + fq * 4 + jj;
            int kk = wv - rl;
            float sc = -1e30f;
            if (kk >= 0 && kk <= 48) {
                float rel = fabsf((float)kk - 24.f);
                float msk = sigmoidf_((wd - rel) * sh);
                sc = sacc[mf][jj] * 0.125f - (1.f - msk) * 10000.f;
            }
            vals[mf * 4 + jj] = sc;
            mx = fmaxf(mx, sc);
        }
    }
    mx = fmaxf(mx, __shfl_xor(mx, 16, 64));
    mx = fmaxf(mx, __shfl_xor(mx, 32, 64));
    float sum = 0.f;
    #pragma unroll
    for (int i = 0; i < 28; ++i) {
        float e = __expf(vals[i] - mx);
        vals[i] = e;
        sum += e;
    }
    sum += __shfl_xor(sum, 16, 64);
    sum += __shfl_xor(sum, 32, 64);
    float rs = 1.f / sum;

    #pragma unroll
    for (int mf = 0; mf < 7; ++mf) {
        unsigned int lo_ = (unsigned int)f2bf(vals[mf * 4 + 0] * rs)
                         | ((unsigned int)f2bf(vals[mf * 4 + 1] * rs) << 16);
        unsigned int hi_ = (unsigned int)f2bf(vals[mf * 4 + 2] * rs)
                         | ((unsigned int)f2bf(vals[mf * 4 + 3] * rs) << 16);
        *(uint2*)&P_A[rl][mf * 16 + fq * 4] = make_uint2(lo_, hi_);
    }

    // ---- PV
    f32x4 oacc[4];
    #pragma unroll
    for (int nf = 0; nf < 4; ++nf) oacc[nf] = (f32x4){0.f, 0.f, 0.f, 0.f};
    #pragma unroll
    for (int ks = 0; ks < 4; ++ks) {
        bf16x8 ap = *(const bf16x8*)&P_A[wid * 16 + fr][ks * 32 + fq * 8];
        #pragma unroll
        for (int nf = 0; nf < 4; ++nf) {
            bf16x8 bv = *(const bf16x8*)&Vt[nf * 16 + fr][ks * 32 + fq * 8];
            oacc[nf] = __builtin_amdgcn_mfma_f32_16x16x32_bf16(ap, bv, oacc[nf], 0, 0, 0);
        }
    }

    const int orow = n0 + wid * 16 + fq * 4;
    #pragma unroll
    for (int nf = 0; nf < 4; ++nf)
        #pragma unroll
        for (int jj = 0; jj < 4; ++jj)
            att[(size_t)(orow + jj) * 512 + h * 64 + nf * 16 + fr] = oacc[nf][jj];
}

// ---------------------------------------------------------------------------
__global__ __launch_bounds__(256) void inv_rms(
    const float* __restrict__ att, float* __restrict__ inv)
{
    const int n = blockIdx.x * 4 + (threadIdx.x >> 6);
    const int lane = threadIdx.x & 63;
    const float4* p = (const float4*)(att + (size_t)n * 512 + lane * 8);
    float4 a = p[0], c = p[1];
    float ss = a.x*a.x + a.y*a.y + a.z*a.z + a.w*a.w
             + c.x*c.x + c.y*c.y + c.z*c.z + c.w*c.w;
    #pragma unroll
    for (int m = 32; m; m >>= 1) ss += __shfl_xor(ss, m, 64);
    if (lane == 0) inv[n] = rsqrtf(ss * (1.f / 512.f) + 1e-6f);
}

// ---------------------------------------------------------------------------
extern "C" void kernel_launch(void* const* d_in, const int* in_sizes, int n_in,
                              void* d_out, int out_size, void* d_ws, size_t ws_size,
                              hipStream_t stream)
{
    const float* x    = (const float*)d_in[0];
    const float* Wq   = (const float*)d_in[1];
    const float* Wkv  = (const float*)d_in[2];
    const float* Wwin = (const float*)d_in[3];
    const float* bwin = (const float*)d_in[4];
    const float* Wg   = (const float*)d_in[5];
    const float* bg   = (const float*)d_in[6];
    const float* Wout = (const float*)d_in[7];
    const float* qn_w = (const float*)d_in[8];
    const float* kn_w = (const float*)d_in[9];
    const float* on_w = (const float*)d_in[10];
    float* outp = (float*)d_out;

    unsigned short* xbf  = (unsigned short*)d_ws;            // 8192*512
    unsigned short* qb   = xbf  + (size_t)NROW * 512;        // 8192*512
    unsigned short* kpad = qb   + (size_t)NROW * 512;        // 2*4144*512
    unsigned short* vpad = kpad + (size_t)2 * LP * 512;      // 2*4144*512
    unsigned short* wqb  = vpad + (size_t)2 * LP * 512;      // 512*512
    unsigned short* wkvb = wqb  + 512 * 512;                 // 1024*512
    unsigned short* wgb  = wkvb + 1024 * 512;                // 512*512
    unsigned short* woutb= wgb  + 512 * 512;                 // 512*512
    unsigned short* wwinb= woutb+ 512 * 512;                 // 64*512
    float* wpb  = (float*)(wwinb + 64 * 512);                // 8192*16 f32
    float* invb = wpb + (size_t)NROW * 16;                   // 8192 f32
    unsigned short* mbf = xbf;                               // reuse xbf after qkv
    float* att = outp;                                       // reuse d_out

    dim3 blk(256);

    zero_pads<<<dim3(48), blk, 0, stream>>>(kpad, vpad);
    conv_bf16<<<dim3(NROW * 512 / 4 / 256), blk, 0, stream>>>(x, xbf, NROW * 512 / 4);
    conv_w5<<<dim3(256, 5), blk, 0, stream>>>(Wq, Wkv, Wg, Wout, wqb, wkvb, wgb, woutb);
    conv_wwin<<<dim3(128), blk, 0, stream>>>(Wwin, wwinb);

    // fused q+kv+wp projections; BM=64, triple-buffer counted-vmcnt
    mfma_gemm<10, 64, false><<<dim3(25, 128), blk, 0, stream>>>(
        xbf, wqb, wkvb, wwinb, wpb, qb, kpad, vpad, bwin, nullptr, qn_w, kn_w);

    attn_fused<<<dim3(1024), blk, 0, stream>>>(qb, kpad, vpad, wpb, att);

    inv_rms<<<dim3(NROW / 4), blk, 0, stream>>>(att, invb);

    // gate-merge -> bf16 merged (A = vpad, remapped rows)
    mfma_gemm<3, 64, true><<<dim3(8, 128), blk, 0, stream>>>(
        vpad, wgb, nullptr, nullptr, nullptr, mbf, nullptr, nullptr,
        bg, att, invb, on_w);

    // final projection -> d_out (f32)
    mfma_gemm<0, 64, false><<<dim3(8, 128), blk, 0, stream>>>(
        mbf, woutb, nullptr, nullptr, outp, nullptr, nullptr, nullptr,
        nullptr, nullptr, nullptr, nullptr);
}

// Round 14
// 76.887 us; speedup vs baseline: 1.1794x; 1.1794x over previous
//
#include <hip/hip_runtime.h>
#include <math.h>

#define L_ 4096
#define NROW 8192   // B*L
#define LP 4144     // L + 48 (24 pad each side)

typedef __attribute__((ext_vector_type(8))) short bf16x8;
typedef __attribute__((ext_vector_type(4))) float f32x4;

__device__ __forceinline__ float sigmoidf_(float x) { return 1.f / (1.f + __expf(-x)); }
__device__ __forceinline__ float siluf_(float x) { return x * sigmoidf_(x); }

__device__ __forceinline__ unsigned short f2bf(float x) {
    union { float f; unsigned int u; } v; v.f = x;
    unsigned int r = v.u + 0x7fff + ((v.u >> 16) & 1);   // RNE
    return (unsigned short)(r >> 16);
}
__device__ __forceinline__ float bf2f(unsigned short u) {
    union { unsigned int u; float f; } v; v.u = ((unsigned int)u) << 16;
    return v.f;
}

__device__ __forceinline__ void gll16(const void* g, void* l) {
    auto gp = reinterpret_cast<const __attribute__((address_space(1))) unsigned int*>(
        reinterpret_cast<uintptr_t>(g));
    auto lp = reinterpret_cast<__attribute__((address_space(3))) unsigned int*>(
        reinterpret_cast<uintptr_t>(l));
    __builtin_amdgcn_global_load_lds(gp, lp, 16, 0, 0);
}

// ---------------------------------------------------------------------------
// bf16 MFMA GEMM (NT), K=512, BN=64, BK=64 (128B rows), BM in {128,64},
// 4 waves stacked. 2-phase double buffer (8 K-steps) — r10's verified-best
// structure. In-row XOR swizzle: staging lane->(row=lane>>3,
// slot=(lane&7)^(row&7)) keeps 128B row segments intact (coalesced) while
// fragment reads (slot=(ks*4+fq)^(fr&7)) are bank-conflict-free
// (r10-verified: SQ_LDS_BANK_CONFLICT = 0).
// EPI 0:  silu -> outF f32 [row*512+col]                    (out-proj)
// EPI 3:  gate: g=sigmoid(silu(acc+bias[col])); vv=bf2f(A_pad[row,col]);
//         oo=extraF0[row*512+col]*extraF1[row]*extraF2[col];
//         outB0 = bf16(g*vv + (1-g)*oo)                     (A = vpad, APAD)
// EPI 10: fused qkv+wp. bn/512 = kind: 0 q (rms+rope->outB0),
//         1 k (rms+rope->kpad outB1), 2 v (silu->vpad outB2),
//         3 wp (silu(acc+bias)->outF[row*16+fr]).
// ---------------------------------------------------------------------------
template<int EPI, int BM, bool APAD>
__global__ __launch_bounds__(256) void mfma_gemm(
    const unsigned short* __restrict__ A,
    const unsigned short* __restrict__ W0,
    const unsigned short* __restrict__ W1,
    const unsigned short* __restrict__ W2,
    float* __restrict__ outF,
    unsigned short* __restrict__ outB0,
    unsigned short* __restrict__ outB1,
    unsigned short* __restrict__ outB2,
    const float* __restrict__ bias,
    const float* __restrict__ extraF0,
    const float* __restrict__ extraF1,
    const float* __restrict__ extraF2)
{
    constexpr int MF = BM / 64;          // m-frags per wave
    constexpr int WR = BM / 4;           // rows per wave
    constexpr int BUFSZ = BM * 128 + 8192;
    __shared__ __align__(128) unsigned char lds[2][BUFSZ];

    const int tid = threadIdx.x;
    const int wid = tid >> 6, lane = tid & 63;
    const int fr = lane & 15, fq = lane >> 4;

    // XCD-aware bijective swizzle (nwg % 8 == 0)
    const int nwg = gridDim.x * gridDim.y;
    const int lin = blockIdx.y * gridDim.x + blockIdx.x;
    const int mapped = (lin & 7) * (nwg >> 3) + (lin >> 3);
    const int bx = mapped % gridDim.x, by = mapped / gridDim.x;
    const int bm = by * BM, bn = bx * 64;

    const unsigned short* Wsel = W0;
    int bnl = bn;
    if (EPI == 10) {
        int kind = bn >> 9;
        if (kind == 0)      { Wsel = W0; bnl = bn; }
        else if (kind <= 2) { Wsel = W1; bnl = bn - 512; }
        else                { Wsel = W2; bnl = bn - 1536; }
    }

    const int apadoff = APAD ? (24 + (bm >> 12) * 48) : 0;
    // staging: lane -> (row = lane>>3, slot = (lane&7)^(row&7)); 128B segments
    const int srow = lane >> 3;
    const int sslot = (lane & 7) ^ srow;
    const unsigned char* gA = (const unsigned char*)A +
        (size_t)(bm + apadoff + wid * WR + srow) * 1024 + sslot * 16;
    const unsigned char* gB = (const unsigned char*)Wsel +
        (size_t)(bnl + wid * 16 + srow) * 1024 + sslot * 16;

    f32x4 acc[MF][4];
    #pragma unroll
    for (int m = 0; m < MF; ++m)
        #pragma unroll
        for (int n = 0; n < 4; ++n)
            acc[m][n] = (f32x4){0.f, 0.f, 0.f, 0.f};

    auto STAGE = [&](int bsel, int k0) {
        unsigned char* lA = lds[bsel] + wid * (WR * 128);
        unsigned char* lB = lds[bsel] + BM * 128 + wid * 2048;
        #pragma unroll
        for (int it = 0; it < WR / 8; ++it)
            gll16(gA + (size_t)it * 8 * 1024 + k0 * 2, lA + it * 1024);
        #pragma unroll
        for (int it = 0; it < 2; ++it)
            gll16(gB + (size_t)it * 8 * 1024 + k0 * 2, lB + it * 1024);
    };
    auto COMPUTE = [&](int bsel) {
        const unsigned char* As = lds[bsel];
        const unsigned char* Bs = lds[bsel] + BM * 128;
        bf16x8 af[MF][2], bfv[4][2];
        #pragma unroll
        for (int m = 0; m < MF; ++m) {
            int ra = wid * WR + m * 16 + fr;
            #pragma unroll
            for (int ks = 0; ks < 2; ++ks)
                af[m][ks] = *(const bf16x8*)(As + ra * 128 + (((ks * 4 + fq) ^ (fr & 7)) << 4));
        }
        #pragma unroll
        for (int n = 0; n < 4; ++n) {
            int rbr = n * 16 + fr;
            #pragma unroll
            for (int ks = 0; ks < 2; ++ks)
                bfv[n][ks] = *(const bf16x8*)(Bs + rbr * 128 + (((ks * 4 + fq) ^ (fr & 7)) << 4));
        }
        #pragma unroll
        for (int ks = 0; ks < 2; ++ks)
            #pragma unroll
            for (int m = 0; m < MF; ++m)
                #pragma unroll
                for (int n = 0; n < 4; ++n)
                    acc[m][n] = __builtin_amdgcn_mfma_f32_16x16x32_bf16(
                        af[m][ks], bfv[n][ks], acc[m][n], 0, 0, 0);
    };

    // 2-phase double buffer over 8 K-steps of 64
    STAGE(0, 0);
    __syncthreads();
    #pragma unroll
    for (int s = 0; s < 7; ++s) {
        STAGE((s + 1) & 1, (s + 1) * 64);
        COMPUTE(s & 1);
        __syncthreads();
    }
    COMPUTE(1);

    const int rb = bm + wid * WR + fq * 4;

    if (EPI == 10) {
        const int kind = bn >> 9;
        if (kind <= 1) {
            // rms + rope fused epilogue (wave column strip == one head)
            const float* nw = (kind == 0) ? extraF1 : extraF2;
            const float nw0 = nw[fr], nw1 = nw[16 + fr], nw2 = nw[32 + fr], nw3 = nw[48 + fr];
            const int hh = (bn & 511) >> 6;
            const float lg = -0.41524101186092029f;   // -log2(10000)/32
            float f0 = exp2f(lg * (float)fr);
            float f1 = exp2f(lg * (float)(16 + fr));
            float s0, c0, s1, c1;
            __sincosf((float)hh * f0, &s0, &c0);
            __sincosf((float)hh * f1, &s1, &c1);
            unsigned short* dstb = (kind == 0) ? outB0 : outB1;
            #pragma unroll
            for (int m = 0; m < MF; ++m) {
                #pragma unroll
                for (int j = 0; j < 4; ++j) {
                    int row = rb + m * 16 + j;
                    float v0 = siluf_(acc[m][0][j]);
                    float v1 = siluf_(acc[m][1][j]);
                    float v2 = siluf_(acc[m][2][j]);
                    float v3 = siluf_(acc[m][3][j]);
                    float ss = v0 * v0 + v1 * v1 + v2 * v2 + v3 * v3;
                    ss += __shfl_xor(ss, 1, 64);
                    ss += __shfl_xor(ss, 2, 64);
                    ss += __shfl_xor(ss, 4, 64);
                    ss += __shfl_xor(ss, 8, 64);
                    float inv = rsqrtf(ss * (1.f / 64.f) + 1e-6f);
                    float y0 = v0 * inv * nw0, y1 = v1 * inv * nw1;
                    float y2 = v2 * inv * nw2, y3 = v3 * inv * nw3;
                    float o0 = y0 * c0 - y2 * s0;
                    float o1 = y1 * c1 - y3 * s1;
                    float o2 = y0 * s0 + y2 * c0;
                    float o3 = y1 * s1 + y3 * c1;
                    size_t rr = (kind == 0) ? (size_t)row
                                            : (size_t)(row + 24 + (row >> 12) * 48);
                    unsigned short* dp = dstb + rr * 512 + hh * 64 + fr;
                    dp[0]  = f2bf(o0);
                    dp[16] = f2bf(o1);
                    dp[32] = f2bf(o2);
                    dp[48] = f2bf(o3);
                }
            }
        } else if (kind == 2) {
            #pragma unroll
            for (int m = 0; m < MF; ++m)
                #pragma unroll
                for (int j = 0; j < 4; ++j) {
                    int row = rb + m * 16 + j;
                    size_t rr = (size_t)(row + 24 + (row >> 12) * 48);
                    #pragma unroll
                    for (int n = 0; n < 4; ++n) {
                        int lc = (bn - 1024) + n * 16 + fr;
                        outB2[rr * 512 + lc] = f2bf(siluf_(acc[m][n][j]));
                    }
                }
        } else {
            // wp: only cols 1536..1551 (n==0, fr 0..15)
            #pragma unroll
            for (int m = 0; m < MF; ++m)
                #pragma unroll
                for (int j = 0; j < 4; ++j) {
                    int row = rb + m * 16 + j;
                    outF[(size_t)row * 16 + fr] = siluf_(acc[m][0][j] + bias[fr]);
                }
        }
    } else {
        #pragma unroll
        for (int m = 0; m < MF; ++m) {
            #pragma unroll
            for (int j = 0; j < 4; ++j) {
                int row = rb + m * 16 + j;
                #pragma unroll
                for (int n = 0; n < 4; ++n) {
                    int col = bn + n * 16 + fr;
                    float t = acc[m][n][j];
                    if (EPI == 0) {
                        outF[(size_t)row * 512 + col] = siluf_(t);
                    } else {  // EPI 3
                        float g = sigmoidf_(siluf_(t + bias[col]));
                        size_t rr = (size_t)(row + 24 + (row >> 12) * 48);
                        float vv = bf2f(A[rr * 512 + col]);
                        float oo = extraF0[(size_t)row * 512 + col] * extraF1[row] * extraF2[col];
                        outB0[(size_t)row * 512 + col] = f2bf(g * vv + (1.f - g) * oo);
                    }
                }
            }
        }
    }
}

// ---------------------------------------------------------------------------
// One fused prep dispatch: x->bf16, 4 weights->bf16, Wwin pad-convert,
// zero the kpad/vpad borders.  Flat index over 1,396,736 16B work units.
// ---------------------------------------------------------------------------
__global__ __launch_bounds__(256) void prep_all(
    const float* __restrict__ x,
    const float* __restrict__ Wq, const float* __restrict__ Wkv,
    const float* __restrict__ Wg, const float* __restrict__ Wout,
    const float* __restrict__ Wwin,
    unsigned short* __restrict__ xbf,
    unsigned short* __restrict__ wqb, unsigned short* __restrict__ wkvb,
    unsigned short* __restrict__ wgb, unsigned short* __restrict__ woutb,
    unsigned short* __restrict__ wwinb,
    unsigned short* __restrict__ kpad, unsigned short* __restrict__ vpad)
{
    int u = blockIdx.x * 256 + threadIdx.x;
    if (u < 1048576) {                       // x: 8192*512/4 float4s
        float4 v = ((const float4*)x)[u];
        ushort4 o;
        o.x = f2bf(v.x); o.y = f2bf(v.y); o.z = f2bf(v.z); o.w = f2bf(v.w);
        ((ushort4*)xbf)[u] = o;
    } else if (u < 1376256) {                // weights: 327680 float4s
        int off = u - 1048576;
        const float* src; unsigned short* dst;
        if (off < 65536)       { src = Wq;   dst = wqb; }
        else if (off < 196608) { src = Wkv;  dst = wkvb;  off -= 65536; }
        else if (off < 262144) { src = Wg;   dst = wgb;   off -= 196608; }
        else                   { src = Wout; dst = woutb; off -= 262144; }
        float4 v = ((const float4*)src)[off];
        ushort4 o;
        o.x = f2bf(v.x); o.y = f2bf(v.y); o.z = f2bf(v.z); o.w = f2bf(v.w);
        ((ushort4*)dst)[off] = o;
    } else if (u < 1384448) {                // wwin: 64x512 -> 8192 ushort4
        int off = u - 1376256;
        ushort4 o; o.x = 0; o.y = 0; o.z = 0; o.w = 0;
        if (off < 2048) {
            float4 v = ((const float4*)Wwin)[off];
            o.x = f2bf(v.x); o.y = f2bf(v.y); o.z = f2bf(v.z); o.w = f2bf(v.w);
        }
        ((ushort4*)wwinb)[off] = o;
    } else if (u < 1396736) {                // pad zeroing: 12288 8-ushort units
        int t8 = u - 1384448;
        int e = t8 * 8;
        int c = e & 511;
        int t = e >> 9;            // 0..191
        int r48 = t % 48;
        int b = (t / 48) & 1;
        int buf = t / 96;
        int row = b * LP + (r48 < 24 ? r48 : 4096 + r48);
        unsigned short* dst = (buf ? vpad : kpad) + (size_t)row * 512 + c;
        *(uint4*)dst = make_uint4(0u, 0u, 0u, 0u);
    }
}

// ---------------------------------------------------------------------------
// Light fused attention. One block per (b, h, 64-row l-tile), 4 waves.
// ---------------------------------------------------------------------------
__global__ __launch_bounds__(256) void attn_fused(
    const unsigned short* __restrict__ qb,
    const unsigned short* __restrict__ kpad,
    const unsigned short* __restrict__ vpad,
    const float* __restrict__ wpb,
    float* __restrict__ att)
{
    __shared__ __align__(16) unsigned char smem[35328];
    unsigned short* Kl = (unsigned short*)smem;                 // 112x64, swizzled
    auto P_A = (unsigned short(*)[136])smem;                    // overlays K after QK^T
    auto Vt  = (unsigned short(*)[136])(smem + 17408);          // [64][136]
    float* widths = (float*)(smem + 34816);
    float* sharps = (float*)(smem + 35072);

    const int tid = threadIdx.x, wid = tid >> 6, lane = tid & 63;
    const int fr = lane & 15, fq = lane >> 4;
    const int bid = blockIdx.x;
    const int tile = bid & 63, h = (bid >> 6) & 7, b = bid >> 9;
    const int l0 = tile * 64;
    const int n0 = b * L_ + l0;
    const size_t win0 = ((size_t)(b * LP + l0)) * 512;

    // ---- K staging: 896 16B-slots, linear LDS dest, pre-swizzled source
    #pragma unroll
    for (int r = 0; r < 4; ++r) {
        if (r < 3 || wid < 2) {
            int sbase = r * 256 + wid * 64;
            int s = sbase + lane;
            int row = s >> 3;
            int sl = (lane & 7) ^ (row & 7);
            gll16((const unsigned char*)(kpad + win0 + (size_t)row * 512 + h * 64) + sl * 16,
                  smem + sbase * 16);
        }
    }

    // ---- Q frags direct from global
    const unsigned short* qrow = qb + (size_t)(n0 + wid * 16 + fr) * 512 + h * 64 + fq * 8;
    bf16x8 bq0 = *(const bf16x8*)qrow;
    bf16x8 bq1 = *(const bf16x8*)(qrow + 32);

    if (tid < 64) {
        float w_ = wpb[(size_t)(n0 + tid) * 16 + h];
        float s_ = wpb[(size_t)(n0 + tid) * 16 + 8 + h];
        widths[tid] = 24.f * sigmoidf_(w_) + 0.5f;
        sharps[tid] = 9.5f * sigmoidf_(s_) + 0.5f;
    }

    // ---- V transpose staging (quad groups)
    {
        int g = tid & 3, rr = tid >> 2;
        #pragma unroll
        for (int it = 0; it < 2; ++it) {
            int w_ = rr + it * 64;
            if (w_ < 112) {
                const unsigned short* src = vpad + win0 + (size_t)w_ * 512 + h * 64 + g * 16;
                uint4 a = *(const uint4*)src;
                uint4 c = *(const uint4*)(src + 8);
                #pragma unroll
                for (int jj = 0; jj < 4; ++jj) {
                    unsigned int uu = ((unsigned int*)&a)[jj];
                    Vt[g * 16 + jj * 2    ][w_] = (unsigned short)(uu & 0xffff);
                    Vt[g * 16 + jj * 2 + 1][w_] = (unsigned short)(uu >> 16);
                }
                #pragma unroll
                for (int jj = 0; jj < 4; ++jj) {
                    unsigned int uu = ((unsigned int*)&c)[jj];
                    Vt[g * 16 + 8 + jj * 2    ][w_] = (unsigned short)(uu & 0xffff);
                    Vt[g * 16 + 8 + jj * 2 + 1][w_] = (unsigned short)(uu >> 16);
                }
            }
        }
        *(uint2*)&Vt[rr][112 + g * 4] = make_uint2(0u, 0u);
    }

    __syncthreads();

    // ---- QK^T: S^T[w][l], swizzled K reads
    f32x4 sacc[7];
    #pragma unroll
    for (int mf = 0; mf < 7; ++mf) sacc[mf] = (f32x4){0.f, 0.f, 0.f, 0.f};
    #pragma unroll
    for (int mf = 0; mf < 7; ++mf) {
        int row = mf * 16 + fr;
        #pragma unroll
        for (int ks = 0; ks < 2; ++ks) {
            const unsigned short* kp = Kl + (size_t)row * 64 + ((((ks << 2) + fq) ^ (row & 7)) << 3);
            bf16x8 ak = *(const bf16x8*)kp;
            sacc[mf] = (ks == 0)
                ? __builtin_amdgcn_mfma_f32_16x16x32_bf16(ak, bq0, sacc[mf], 0, 0, 0)
                : __builtin_amdgcn_mfma_f32_16x16x32_bf16(ak, bq1, sacc[mf], 0, 0, 0);
        }
    }

    __syncthreads();   // K dead in ALL waves -> P may overlay

    {
        int rr = tid >> 2, g = tid & 3;
        *(uint2*)&P_A[rr][112 + g * 4] = make_uint2(0u, 0u);
    }

    // ---- softmax
    const int rl = wid * 16 + fr;
    const float wd = widths[rl], sh = sharps[rl];
    float vals[28];
    float mx = -1e30f;
    #pragma unroll
    for (int mf = 0; mf < 7; ++mf) {
        #pragma unroll
        for (int jj = 0; jj < 4; ++jj) {
            int wv = mf * 16 + fq * 4 + jj;
            int kk = wv - rl;
            float sc = -1e30f;
            if (kk >= 0 && kk <= 48) {
                float rel = fabsf((float)kk - 24.f);
                float msk = sigmoidf_((wd - rel) * sh);
                sc = sacc[mf][jj] * 0.125f - (1.f - msk) * 10000.f;
            }
            vals[mf * 4 + jj] = sc;
            mx = fmaxf(mx, sc);
        }
    }
    mx = fmaxf(mx, __shfl_xor(mx, 16, 64));
    mx = fmaxf(mx, __shfl_xor(mx, 32, 64));
    float sum = 0.f;
    #pragma unroll
    for (int i = 0; i < 28; ++i) {
        float e = __expf(vals[i] - mx);
        vals[i] = e;
        sum += e;
    }
    sum += __shfl_xor(sum, 16, 64);
    sum += __shfl_xor(sum, 32, 64);
    float rs = 1.f / sum;

    #pragma unroll
    for (int mf = 0; mf < 7; ++mf) {
        unsigned int lo_ = (unsigned int)f2bf(vals[mf * 4 + 0] * rs)
                         | ((unsigned int)f2bf(vals[mf * 4 + 1] * rs) << 16);
        unsigned int hi_ = (unsigned int)f2bf(vals[mf * 4 + 2] * rs)
                         | ((unsigned int)f2bf(vals[mf * 4 + 3] * rs) << 16);
        *(uint2*)&P_A[rl][mf * 16 + fq * 4] = make_uint2(lo_, hi_);
    }

    // ---- PV
    f32x4 oacc[4];
    #pragma unroll
    for (int nf = 0; nf < 4; ++nf) oacc[nf] = (f32x4){0.f, 0.f, 0.f, 0.f};
    #pragma unroll
    for (int ks = 0; ks < 4; ++ks) {
        bf16x8 ap = *(const bf16x8*)&P_A[wid * 16 + fr][ks * 32 + fq * 8];
        #pragma unroll
        for (int nf = 0; nf < 4; ++nf) {
            bf16x8 bv = *(const bf16x8*)&Vt[nf * 16 + fr][ks * 32 + fq * 8];
            oacc[nf] = __builtin_amdgcn_mfma_f32_16x16x32_bf16(ap, bv, oacc[nf], 0, 0, 0);
        }
    }

    const int orow = n0 + wid * 16 + fq * 4;
    #pragma unroll
    for (int nf = 0; nf < 4; ++nf)
        #pragma unroll
        for (int jj = 0; jj < 4; ++jj)
            att[(size_t)(orow + jj) * 512 + h * 64 + nf * 16 + fr] = oacc[nf][jj];
}

// ---------------------------------------------------------------------------
__global__ __launch_bounds__(256) void inv_rms(
    const float* __restrict__ att, float* __restrict__ inv)
{
    const int n = blockIdx.x * 4 + (threadIdx.x >> 6);
    const int lane = threadIdx.x & 63;
    const float4* p = (const float4*)(att + (size_t)n * 512 + lane * 8);
    float4 a = p[0], c = p[1];
    float ss = a.x*a.x + a.y*a.y + a.z*a.z + a.w*a.w
             + c.x*c.x + c.y*c.y + c.z*c.z + c.w*c.w;
    #pragma unroll
    for (int m = 32; m; m >>= 1) ss += __shfl_xor(ss, m, 64);
    if (lane == 0) inv[n] = rsqrtf(ss * (1.f / 512.f) + 1e-6f);
}

// ---------------------------------------------------------------------------
extern "C" void kernel_launch(void* const* d_in, const int* in_sizes, int n_in,
                              void* d_out, int out_size, void* d_ws, size_t ws_size,
                              hipStream_t stream)
{
    const float* x    = (const float*)d_in[0];
    const float* Wq   = (const float*)d_in[1];
    const float* Wkv  = (const float*)d_in[2];
    const float* Wwin = (const float*)d_in[3];
    const float* bwin = (const float*)d_in[4];
    const float* Wg   = (const float*)d_in[5];
    const float* bg   = (const float*)d_in[6];
    const float* Wout = (const float*)d_in[7];
    const float* qn_w = (const float*)d_in[8];
    const float* kn_w = (const float*)d_in[9];
    const float* on_w = (const float*)d_in[10];
    float* outp = (float*)d_out;

    unsigned short* xbf  = (unsigned short*)d_ws;            // 8192*512
    unsigned short* qb   = xbf  + (size_t)NROW * 512;        // 8192*512
    unsigned short* kpad = qb   + (size_t)NROW * 512;        // 2*4144*512
    unsigned short* vpad = kpad + (size_t)2 * LP * 512;      // 2*4144*512
    unsigned short* wqb  = vpad + (size_t)2 * LP * 512;      // 512*512
    unsigned short* wkvb = wqb  + 512 * 512;                 // 1024*512
    unsigned short* wgb  = wkvb + 1024 * 512;                // 512*512
    unsigned short* woutb= wgb  + 512 * 512;                 // 512*512
    unsigned short* wwinb= woutb+ 512 * 512;                 // 64*512
    float* wpb  = (float*)(wwinb + 64 * 512);                // 8192*16 f32
    float* invb = wpb + (size_t)NROW * 16;                   // 8192 f32
    unsigned short* mbf = xbf;                               // reuse xbf after qkv
    float* att = outp;                                       // reuse d_out

    dim3 blk(256);

    // all conversions + pad zeroing in one dispatch (1396736 units / 256)
    prep_all<<<dim3(5456), blk, 0, stream>>>(
        x, Wq, Wkv, Wg, Wout, Wwin,
        xbf, wqb, wkvb, wgb, woutb, wwinb, kpad, vpad);

    // fused q+kv+wp projections with rms+rope epilogue (r10 structure)
    mfma_gemm<10, 128, false><<<dim3(25, 64), blk, 0, stream>>>(
        xbf, wqb, wkvb, wwinb, wpb, qb, kpad, vpad, bwin, nullptr, qn_w, kn_w);

    attn_fused<<<dim3(1024), blk, 0, stream>>>(qb, kpad, vpad, wpb, att);

    inv_rms<<<dim3(NROW / 4), blk, 0, stream>>>(att, invb);

    // gate-merge -> bf16 merged (A = vpad, remapped rows)
    mfma_gemm<3, 64, true><<<dim3(8, 128), blk, 0, stream>>>(
        vpad, wgb, nullptr, nullptr, nullptr, mbf, nullptr, nullptr,
        bg, att, invb, on_w);

    // final projection -> d_out (f32)
    mfma_gemm<0, 64, false><<<dim3(8, 128), blk, 0, stream>>>(
        mbf, woutb, nullptr, nullptr, outp, nullptr, nullptr, nullptr,
        nullptr, nullptr, nullptr, nullptr);
}